// Round 4
// baseline (935.195 us; speedup 1.0000x reference)
//
#include <hip/hip_runtime.h>
#include <hip/hip_bf16.h>
#include <hip/hip_fp16.h>

// ManualRNN: B=32, T=2048, Fin=256, H=256, O=256  (all f32 in/out)
//   phase1: xh = x @ Wxh^T + bxh   -> stored f32 in d_out's y region (dead before phase3)
//   phase2: h_t = tanh(xh_t + h @ Whh^T), scan over T -> hs f16 in d_ws
//   phase3: y  = hs @ Why^T + by   -> overwrites y region
// h_final (32x256 f32) at d_out + 65536*256.
//
// Scan structural floor: 128 MFMA/block/step (M<=16 always costs a full
// 16-row tile) / 4 SIMDs * 19.4 cy = 620 cy/step => >= 528 us. Packing
// batches or N-splitting across CUs cannot beat this (waste cancels /
// cross-CU sync costs more). Optimization target = the non-MFMA serial path.

typedef _Float16 f16x8 __attribute__((ext_vector_type(8)));
typedef float    f32x4 __attribute__((ext_vector_type(4)));

#define MFMA16 __builtin_amdgcn_mfma_f32_16x16x32_f16

__device__ __forceinline__ f16x8 cvt8(const float* __restrict__ p) {
    float4 u = *(const float4*)p;
    float4 v = *(const float4*)(p + 4);
    f16x8 r;
    r[0] = (_Float16)u.x; r[1] = (_Float16)u.y; r[2] = (_Float16)u.z; r[3] = (_Float16)u.w;
    r[4] = (_Float16)v.x; r[5] = (_Float16)v.y; r[6] = (_Float16)v.z; r[7] = (_Float16)v.w;
    return r;
}

// C[m][n] = sum_k A[m][k] * W[n][k] + bias[n];  M = gridDim.x*64, N = K = 256.
template<bool AF16>
__global__ __launch_bounds__(256, 2) void gemm_nt_256(
    const void* __restrict__ Av, const float* __restrict__ W,
    const float* __restrict__ bias, float* __restrict__ C) {
    const int tid = threadIdx.x;
    const int l  = tid & 63;
    const int w  = tid >> 6;
    const int lr = l & 15;
    const int lg = l >> 4;
    const long m0 = (long)blockIdx.x * 64;
    const int  n0 = w * 64;

    f32x4 acc[4][4] = {};

    #pragma unroll
    for (int k = 0; k < 8; ++k) {
        const int kc = k * 32 + lg * 8;
        f16x8 a[4], bf[4];
        #pragma unroll
        for (int mt = 0; mt < 4; ++mt) {
            const long row = m0 + mt * 16 + lr;
            if constexpr (AF16)
                a[mt] = *(const f16x8*)((const _Float16*)Av + row * 256 + kc);
            else
                a[mt] = cvt8((const float*)Av + row * 256 + kc);
        }
        #pragma unroll
        for (int nt = 0; nt < 4; ++nt)
            bf[nt] = cvt8(W + (long)(n0 + nt * 16 + lr) * 256 + kc);
        #pragma unroll
        for (int mt = 0; mt < 4; ++mt)
            #pragma unroll
            for (int nt = 0; nt < 4; ++nt)
                acc[mt][nt] = MFMA16(a[mt], bf[nt], acc[mt][nt], 0, 0, 0);
    }

    #pragma unroll
    for (int mt = 0; mt < 4; ++mt)
        #pragma unroll
        for (int nt = 0; nt < 4; ++nt) {
            const int col = n0 + nt * 16 + lr;
            const float bv = bias[col];
            #pragma unroll
            for (int d = 0; d < 4; ++d) {
                const long row = m0 + mt * 16 + lg * 4 + d;
                C[row * 256 + col] = acc[mt][nt][d] + bv;
            }
        }
}

// Recurrence: 32 blocks (1 batch each) x 512 threads (8 waves, 2/SIMD).
// Wave w owns 32 output cols. Whh B-fragments resident in registers; af
// fragments read via LDS broadcast, pinned BEFORE the MFMA block so all 8
// ds_reads pipeline (only af[0]'s ~120cy latency exposed). LDS-only barrier.
// xh prefetched 4 steps deep. launch_bounds(512,1): no register cap (r3's
// VGPR=72 showed the compiler sinking af reads into the MFMA chain).
__global__ __launch_bounds__(512, 1) void rnn_scan(
    const float* __restrict__ xh, const float* __restrict__ h0,
    const float* __restrict__ Whh, _Float16* __restrict__ hs,
    float* __restrict__ hfin) {
    const int b   = blockIdx.x;
    const int tid = threadIdx.x;
    const int l   = tid & 63;
    const int w   = tid >> 6;   // 0..7
    const int lr  = l & 15;
    const int lg  = l >> 4;
    const int n0  = w * 32;

    __shared__ _Float16 hbuf[2][256];

    // wb[nt][k] = Whh[n0+nt*16+lr][k*32+lg*8 .. +8]  (64 VGPR)
    f16x8 wb[2][8];
    #pragma unroll
    for (int nt = 0; nt < 2; ++nt)
        #pragma unroll
        for (int k = 0; k < 8; ++k)
            wb[nt][k] = cvt8(Whh + (long)(n0 + nt * 16 + lr) * 256 + k * 32 + lg * 8);

    if (tid < 256) hbuf[0][tid] = (_Float16)h0[b * 256 + tid];
    __syncthreads();

    // per-lane column n0 + (l&31); lanes 32-63 duplicate (values unused there)
    const int cl = n0 + (l & 31);
    const float* xp = xh + (long)b * 2048 * 256 + cl;
    _Float16*    hp = hs + (long)b * 2048 * 256 + cl;

    float xcur[4], xnext[4];
    #pragma unroll
    for (int j = 0; j < 4; ++j) xcur[j] = xp[(long)j * 256];

    for (int tb = 0; tb < 2048; tb += 4) {
        // next group's xh loads: ~2500cy of cover >> 900cy HBM latency
        #pragma unroll
        for (int j = 0; j < 4; ++j) {
            long tn = tb + 4 + j; if (tn > 2047) tn = 2047;
            xnext[j] = xp[tn * 256];
        }

        #pragma unroll
        for (int j = 0; j < 4; ++j) {
            const f16x8* hc = (const f16x8*)hbuf[j & 1];   // t&1 == j&1
            f16x8 af[8];
            #pragma unroll
            for (int k = 0; k < 8; ++k) af[k] = hc[k * 4 + lg];
            __builtin_amdgcn_sched_barrier(0);   // all 8 ds_reads issued first

            const f32x4 zero = {0.f, 0.f, 0.f, 0.f};
            f32x4 accA[2], accB[2];              // split chains k0-3 / k4-7
            #pragma unroll
            for (int nt = 0; nt < 2; ++nt) {
                accA[nt] = MFMA16(af[0], wb[nt][0], zero, 0, 0, 0);
                accB[nt] = MFMA16(af[4], wb[nt][4], zero, 0, 0, 0);
            }
            #pragma unroll
            for (int k = 1; k < 4; ++k)
                #pragma unroll
                for (int nt = 0; nt < 2; ++nt) {
                    accA[nt] = MFMA16(af[k],     wb[nt][k],     accA[nt], 0, 0, 0);
                    accB[nt] = MFMA16(af[k + 4], wb[nt][k + 4], accB[nt], 0, 0, 0);
                }

            // single tanh chain: select col's sum first
            const float s0 = accA[0][0] + accB[0][0];
            const float s1 = accA[1][0] + accB[1][0];
            const float s  = ((l & 16) ? s1 : s0) + xcur[j];
            const float e  = __expf(2.0f * s);
            const float v  = 1.0f - 2.0f * __builtin_amdgcn_rcpf(e + 1.0f);
            const _Float16 hv = (_Float16)v;

            if (l < 32) {
                hbuf[(j & 1) ^ 1][cl] = hv;              // critical: next step's h
                hp[(long)(tb + j) * 256] = hv;           // fire-and-forget
            }

            // LDS-only barrier (no vmcnt drain)
            asm volatile("s_waitcnt lgkmcnt(0)" ::: "memory");
            __builtin_amdgcn_s_barrier();
            asm volatile("" ::: "memory");
        }

        #pragma unroll
        for (int j = 0; j < 4; ++j) xcur[j] = xnext[j];
    }

    // t=2047 wrote parity ((2047&1)^1)=0
    if (tid < 256) hfin[b * 256 + tid] = (float)hbuf[0][tid];
}

extern "C" void kernel_launch(void* const* d_in, const int* in_sizes, int n_in,
                              void* d_out, int out_size, void* d_ws, size_t ws_size,
                              hipStream_t stream) {
    const float* x   = (const float*)d_in[0];
    const float* h0  = (const float*)d_in[1];
    const float* Wxh = (const float*)d_in[2];
    const float* bxh = (const float*)d_in[3];
    const float* Whh = (const float*)d_in[4];
    const float* Why = (const float*)d_in[5];
    const float* by  = (const float*)d_in[6];

    float* y    = (float*)d_out;
    float* hfin = y + (long)65536 * 256;
    float* xh   = y;                       // xh scratch aliases y (dead before phase3 writes)
    _Float16* hs = (_Float16*)d_ws;

    gemm_nt_256<false><<<1024, 256, 0, stream>>>(x, Wxh, bxh, xh);
    rnn_scan<<<32, 512, 0, stream>>>(xh, h0, Whh, hs, hfin);
    gemm_nt_256<true><<<1024, 256, 0, stream>>>(hs, Why, by, y);
}